// Round 5
// baseline (229.139 us; speedup 1.0000x reference)
//
#include <hip/hip_runtime.h>

#define HH 4096      // canvas side
#define KK 32        // box / tile side
#define OH 4065      // HH - KK + 1
#define WPS 224      // output cols per wave (mult of 32: jc slab-invariant; 56 lanes x 4 cols)
#define RCH 32       // output rows per wave
#define PF 4         // prefetch depth in rows -> 8 dwordx4 loads (8 KB) in flight/wave

// R5: same wave-autonomous skeleton as R4, but 16 B/lane loads.
// R0/R2/R4 (three different structures, occupancy 9-46%) all pinned at
// ~87 us / 2.2-2.7 TB/s with 4-8 B/lane loads. The 6.3 TB/s copy ubench
// uses 16 B/lane. Hypothesis: DRAM-side efficiency of narrow strided
// bursts is the ceiling; dwordx4 row reads (1 KB/wave-instr, 16 B-aligned
// since som rows are 16 KB-aligned and c0 % 4 == 0) is the fix.
// Each lane owns 4 consecutive cols: ring = float4[32] (static-indexed,
// 128 VGPR). Horizontal 32-window: quad suffix tree (3 shfl) + 3 prefix
// partials from lane+8. Stores stay scalar dword (OH odd -> vector stores
// would be misaligned; writes are only 66 MB).
__global__ __launch_bounds__(64) void som_wave4(
    const float* __restrict__ img,   // 32x32
    const float* __restrict__ som,   // 4096x4096
    const float* __restrict__ var,   // 4096x4096
    float* __restrict__ out)         // 4065x4065
{
    __shared__ float simg[KK * KK];  // 4 KB, read-only after init
    const int l = threadIdx.x;       // 0..63
    for (int i = l; i < KK * KK; i += 64) simg[i] = img[i];
    __syncthreads();                 // once; single wave, nearly free

    const int slab = blockIdx.x;             // 0..18
    const int r0   = blockIdx.y * RCH;       // 0..4064 (multiple of 32)
    const int c0   = slab * WPS + 4 * l;     // lane's first col (input & output)
    const int c0c  = c0 <= HH - 4 ? c0 : HH - 4;   // float4-safe clamp (last slab
                                             // halo lanes only; never feeds valid out)
    const int jc   = (4 * l) & (KK - 1);     // c0 % 32 (WPS % 32 == 0), mult of 4
    const bool lv  = (4 * l) < WPS;          // lane owns output cols (l <= 55)
    const bool m0  = lv && (c0     <= OH - 1);
    const bool m1  = lv && (c0 + 1 <= OH - 1);
    const bool m2  = lv && (c0 + 2 <= OH - 1);
    const bool m3  = lv && (c0 + 3 <= OH - 1);
    const int rlimit = (r0 + RCH - 1 < OH) ? (r0 + RCH - 1) : (OH - 1);

    // 32-bit byte offsets, SGPR-base + VGPR-voffset addressing
    unsigned voff = (unsigned)(r0 * HH + c0c) * 4u;
    const unsigned vmax  = (unsigned)((HH - 1) * HH + c0c) * 4u;  // row clamp
    const unsigned vstep = HH * 4u;
    unsigned vstore = (unsigned)(r0 * OH + c0) * 4u;   // masked lanes never deref

    // ---- prologue: fill prefetch pipe with rows r0 .. r0+PF-1 ----
    float4 pfs[PF], pfv[PF];
#pragma unroll
    for (int p = 0; p < PF; ++p) {
        pfs[p] = *(const float4*)((const char*)som + voff);
        pfv[p] = *(const float4*)((const char*)var + voff);
        voff = (voff + vstep <= vmax) ? voff + vstep : vmax;
    }

    float4 ring[KK];                 // static-indexed under full unroll -> VGPRs
    float4 w;                        // running vertical window sum per col
    w.x = 0.f; w.y = 0.f; w.z = 0.f; w.w = 0.f;

#define EMIT()                                                              \
    do {                                                                    \
        float pr = w.x + w.y + w.z + w.w;                                   \
        pr += __shfl_down(pr, 1, 64);                                       \
        pr += __shfl_down(pr, 2, 64);                                       \
        pr += __shfl_down(pr, 4, 64);  /* suffix over 8 quads = 32 cols */  \
        const float p1 = w.x;                                               \
        const float p2 = w.x + w.y;                                         \
        const float p3 = p2 + w.z;                                          \
        const float s1 = __shfl_down(p1, 8, 64);                            \
        const float s2 = __shfl_down(p2, 8, 64);                            \
        const float s3 = __shfl_down(p3, 8, 64);                            \
        if (m0) *(float*)((char*)out + vstore)      = pr;                   \
        if (m1) *(float*)((char*)out + vstore + 4)  = pr - p1 + s1;         \
        if (m2) *(float*)((char*)out + vstore + 8)  = pr - p2 + s2;         \
        if (m3) *(float*)((char*)out + vstore + 12) = pr - p3 + s3;         \
    } while (0)

    // ---- init peel: input rows r0+0 .. r0+31; emit output row r0 at k=31 ----
#pragma unroll
    for (int k = 0; k < KK; ++k) {
        const int slot = k & (PF - 1);
        const float4 s4 = pfs[slot];
        const float4 v4 = pfv[slot];
        pfs[slot] = *(const float4*)((const char*)som + voff);
        pfv[slot] = *(const float4*)((const char*)var + voff);
        voff = (voff + vstep <= vmax) ? voff + vstep : vmax;

        const float4 im = *(const float4*)&simg[(k << 5) + jc]; // (r0+k)%32==k
        float4 d;
        d.x = (im.x - s4.x) * (im.x - s4.x) * __builtin_amdgcn_rcpf(v4.x + 1e-8f);
        d.y = (im.y - s4.y) * (im.y - s4.y) * __builtin_amdgcn_rcpf(v4.y + 1e-8f);
        d.z = (im.z - s4.z) * (im.z - s4.z) * __builtin_amdgcn_rcpf(v4.z + 1e-8f);
        d.w = (im.w - s4.w) * (im.w - s4.w) * __builtin_amdgcn_rcpf(v4.w + 1e-8f);
        w.x += d.x; w.y += d.y; w.z += d.z; w.w += d.w;

        if (k == KK - 1) {
            EMIT();                              // output row r0
            vstore += OH * 4u;
            w.x -= ring[0].x; w.y -= ring[0].y;  // drop input row r0
            w.z -= ring[0].z; w.w -= ring[0].w;
        }
        ring[k] = d;
    }

    // ---- main: ir = 32..62, emit output row r0+ir-31 (r0+1 .. r0+31) ----
#pragma unroll
    for (int ir = KK; ir < KK + RCH - 1; ++ir) {
        const int slot = ir & (PF - 1);
        const float4 s4 = pfs[slot];
        const float4 v4 = pfv[slot];
        pfs[slot] = *(const float4*)((const char*)som + voff);
        pfv[slot] = *(const float4*)((const char*)var + voff);
        voff = (voff + vstep <= vmax) ? voff + vstep : vmax;

        const float4 im = *(const float4*)&simg[((ir & (KK - 1)) << 5) + jc];
        float4 d;
        d.x = (im.x - s4.x) * (im.x - s4.x) * __builtin_amdgcn_rcpf(v4.x + 1e-8f);
        d.y = (im.y - s4.y) * (im.y - s4.y) * __builtin_amdgcn_rcpf(v4.y + 1e-8f);
        d.z = (im.z - s4.z) * (im.z - s4.z) * __builtin_amdgcn_rcpf(v4.z + 1e-8f);
        d.w = (im.w - s4.w) * (im.w - s4.w) * __builtin_amdgcn_rcpf(v4.w + 1e-8f);
        w.x += d.x; w.y += d.y; w.z += d.z; w.w += d.w;

        if (r0 + ir - (KK - 1) <= rlimit) {      // uniform scalar branch
            EMIT();
        }
        vstore += OH * 4u;
        // drop oldest input row (ir-31): slot (ir-31)&31 == (ir+1)&31
        const int dr = (ir + 1) & (KK - 1);
        w.x -= ring[dr].x; w.y -= ring[dr].y;
        w.z -= ring[dr].z; w.w -= ring[dr].w;
        ring[ir & (KK - 1)] = d;                 // slot held row ir-32 (dead)
    }
#undef EMIT
}

extern "C" void kernel_launch(void* const* d_in, const int* in_sizes, int n_in,
                              void* d_out, int out_size, void* d_ws, size_t ws_size,
                              hipStream_t stream) {
    (void)in_sizes; (void)n_in; (void)out_size; (void)d_ws; (void)ws_size;
    const float* img = (const float*)d_in[0];   // 32x32
    const float* som = (const float*)d_in[1];   // 4096x4096
    const float* var = (const float*)d_in[2];   // 4096x4096
    float* out = (float*)d_out;                 // 4065x4065

    dim3 blk(64);                                // one wave per block
    dim3 grd((OH + WPS - 1) / WPS,               // 19 column slabs
             (OH + RCH - 1) / RCH);              // 128 row chunks
    hipLaunchKernelGGL(som_wave4, grd, blk, 0, stream, img, som, var, out);
}

// Round 6
// 208.603 us; speedup vs baseline: 1.0984x; 1.0984x over previous
//
#include <hip/hip_runtime.h>

#define HH 4096      // canvas side
#define KK 32        // box / tile side
#define OH 4065      // HH - KK + 1
#define WPS 96       // output cols per wave (48 lanes x 2 cols + 16-lane halo)
#define RCH 64       // output rows per wave
#define WV  4        // independent waves per 256-thread block (no barriers)
#define PF  16       // prefetch depth in rows -> 32 float2 loads (16KB) in flight/wave

// R6: discriminating experiment for the MLP hypothesis.
// R4 (float2, PF=8, 1-wave blocks)  : 88us, 2.42 TB/s
// R5 (float4, PF=4, 1-wave blocks)  : 117us, 1.86 TB/s  <- wider bursts but
//   HALF the outstanding loads; slower => burst-width theory refuted, MLP
//   (pipeline depth) is the live suspect along with wave under-residency
//   (occupancy counter showed ~3 waves/CU resident vs 10.75 supplied).
// R6 = R4 skeleton with (1) PF 16: 32 loads / 16KB in flight per wave and
// (2) 4 independent waves packed per 256-thread workgroup (fixes potential
// single-wave workgroup under-packing). Same total wave count as R4 (2752).
// If BW stays ~2.4 TB/s despite 2-4x in-flight bytes, the access SHAPE
// (16KB-strided column bands) is the ceiling -> pivot to linear two-pass.
__global__ __launch_bounds__(256) void som_wave_p(
    const float* __restrict__ img,   // 32x32
    const float* __restrict__ som,   // 4096x4096
    const float* __restrict__ var,   // 4096x4096
    float* __restrict__ out)         // 4065x4065
{
    __shared__ float simg[KK * KK];  // 4 KB, read-only after init
    const int tid = threadIdx.x;
    const int l   = tid & 63;        // lane
    const int w   = tid >> 6;        // wave id 0..3
    for (int i = tid; i < KK * KK; i += 256) simg[i] = img[i];
    __syncthreads();                 // once; waves are independent after this

    const int slab = blockIdx.x;                   // 0..42
    const int r0   = (blockIdx.y * WV + w) * RCH;  // this wave's row chunk
    const int c0   = slab * WPS + 2 * l;           // lane's even column
    const int c0c  = c0 <= HH - 2 ? c0 : HH - 2;   // float2-safe clamp
    const int jc0  = c0c & (KK - 1);
    const bool maskE = (l <= 47) && (c0     <= OH - 1);
    const bool maskO = (l <= 47) && (c0 + 1 <= OH - 1);
    const int rlimit = (r0 + RCH - 1 < OH) ? r0 + RCH - 1 : OH - 1;

    // 32-bit byte offsets, SGPR-base + VGPR-voffset addressing
    unsigned voff = (unsigned)(r0 * HH + c0c) * 4u;
    const unsigned vmax  = (unsigned)((HH - 1) * HH + c0c) * 4u;  // row clamp
    const unsigned vstep = HH * 4u;
    unsigned vstore = (unsigned)(r0 * OH + c0) * 4u;

    // ---- prologue: fill prefetch pipe with rows r0 .. r0+PF-1 ----
    float2 pfs[PF], pfv[PF];
#pragma unroll
    for (int p = 0; p < PF; ++p) {
        pfs[p] = *(const float2*)((const char*)som + voff);
        pfv[p] = *(const float2*)((const char*)var + voff);
        voff = (voff + vstep <= vmax) ? voff + vstep : vmax;
    }

    float ring0[KK], ring1[KK];      // static-indexed -> stays in VGPRs
    float sum0 = 0.f, sum1 = 0.f;

    // ---- init peel: steps k = 0..31 (input rows r0+k); emit only k==31 ----
    // slot k&15 holds row r0+k (prologue for k<16, refilled at step k-16).
#pragma unroll
    for (int k = 0; k < KK; ++k) {
        const int slot = k & (PF - 1);
        const float2 s2 = pfs[slot];
        const float2 v2 = pfv[slot];
        pfs[slot] = *(const float2*)((const char*)som + voff);  // row r0+k+16
        pfv[slot] = *(const float2*)((const char*)var + voff);
        voff = (voff + vstep <= vmax) ? voff + vstep : vmax;

        const float2 im = *(const float2*)&simg[(k << 5) | jc0]; // (r0+k)%32==k
        const float e0 = im.x - s2.x;
        const float d0 = e0 * e0 * __builtin_amdgcn_rcpf(v2.x + 1e-8f);
        const float e1 = im.y - s2.y;
        const float d1 = e1 * e1 * __builtin_amdgcn_rcpf(v2.y + 1e-8f);
        const float V0 = sum0 + d0;
        const float V1 = sum1 + d1;
        if (k == KK - 1) {
            // emit output row r0
            float pr = V0 + V1;                       // pair sum: cols 2l,2l+1
            pr += __shfl_down(pr, 1, 64);
            pr += __shfl_down(pr, 2, 64);
            pr += __shfl_down(pr, 4, 64);
            pr += __shfl_down(pr, 8, 64);             // 16 pairs = 32-col window
            const float ev = pr;                      // out col c0
            const float od = ev - V0 + __shfl_down(V0, 16, 64); // out col c0+1
            if (maskE) *(float*)((char*)out + vstore)     = ev;
            if (maskO) *(float*)((char*)out + vstore + 4) = od;
            vstore += OH * 4u;
            sum0 = V0 - ring0[0];                     // drop input row r0
            sum1 = V1 - ring1[0];
        } else {
            sum0 = V0;
            sum1 = V1;
        }
        ring0[k] = d0;
        ring1[k] = d1;
    }

    // ---- main: o = 1..2, steps ir = o*32+k; emit row rout = r0+ir-31 ----
    // 32 % 16 == 0 and 32 % 32 == 0 -> slot (ir&15)=k&15 and ring idx (ir&31)=k
    // are compile-time constants in every outer iteration.
#pragma unroll 1
    for (int o = 1; o < 3; ++o) {
#pragma unroll
        for (int k = 0; k < KK; ++k) {
            const int slot = k & (PF - 1);
            const float2 s2 = pfs[slot];
            const float2 v2 = pfv[slot];
            pfs[slot] = *(const float2*)((const char*)som + voff);
            pfv[slot] = *(const float2*)((const char*)var + voff);
            voff = (voff + vstep <= vmax) ? voff + vstep : vmax;

            const float2 im = *(const float2*)&simg[(k << 5) | jc0];
            const float e0 = im.x - s2.x;
            const float d0 = e0 * e0 * __builtin_amdgcn_rcpf(v2.x + 1e-8f);
            const float e1 = im.y - s2.y;
            const float d1 = e1 * e1 * __builtin_amdgcn_rcpf(v2.y + 1e-8f);
            const float V0 = sum0 + d0;
            const float V1 = sum1 + d1;

            const int rout = r0 + o * KK + k - (KK - 1);
            if (rout <= rlimit) {                     // uniform scalar branch
                float pr = V0 + V1;
                pr += __shfl_down(pr, 1, 64);
                pr += __shfl_down(pr, 2, 64);
                pr += __shfl_down(pr, 4, 64);
                pr += __shfl_down(pr, 8, 64);
                const float ev = pr;
                const float od = ev - V0 + __shfl_down(V0, 16, 64);
                if (maskE) *(float*)((char*)out + vstore)     = ev;
                if (maskO) *(float*)((char*)out + vstore + 4) = od;
            }
            vstore += OH * 4u;
            // slide window: drop oldest input row (slot (k+1)&31)
            sum0 = V0 - ring0[(k + 1) & (KK - 1)];
            sum1 = V1 - ring1[(k + 1) & (KK - 1)];
            ring0[k] = d0;
            ring1[k] = d1;
        }
    }
}

extern "C" void kernel_launch(void* const* d_in, const int* in_sizes, int n_in,
                              void* d_out, int out_size, void* d_ws, size_t ws_size,
                              hipStream_t stream) {
    (void)in_sizes; (void)n_in; (void)out_size; (void)d_ws; (void)ws_size;
    const float* img = (const float*)d_in[0];   // 32x32
    const float* som = (const float*)d_in[1];   // 4096x4096
    const float* var = (const float*)d_in[2];   // 4096x4096
    float* out = (float*)d_out;                 // 4065x4065

    dim3 blk(256);                               // 4 independent waves per block
    dim3 grd((OH + WPS - 1) / WPS,               // 43 column slabs
             (OH + WV * RCH - 1) / (WV * RCH));  // 16 row super-chunks
    hipLaunchKernelGGL(som_wave_p, grd, blk, 0, stream, img, som, var, out);
}